// Round 5
// baseline (13197.604 us; speedup 1.0000x reference)
//
#include <hip/hip_runtime.h>

#define NROWS 32768   // B*T = 16*2048
#define DIM 256
#define KCODES 1024
#define NLEV 4
#define DTILE 32      // d-slice per staged tile
#define RTILE 128     // rows per block

// ============ codebook squared norms (bit-identical to passing rounds) ============
__global__ __launch_bounds__(256) void k_bnorm(const float* __restrict__ cb,
                                               float* __restrict__ bv) {
  int r = blockIdx.x * blockDim.x + threadIdx.x;  // 0..4095
  if (r >= NLEV * KCODES) return;
  const float4* p = reinterpret_cast<const float4*>(cb + (size_t)r * DIM);
  float s0 = 0.f, s1 = 0.f, s2 = 0.f, s3 = 0.f;
  for (int g = 0; g < DIM / 4; ++g) {
    float4 v = p[g];
    s0 += v.x * v.x; s1 += v.y * v.y; s2 += v.z * v.z; s3 += v.w * v.w;
  }
  bv[r] = (s0 + s1) + (s2 + s3);
}

// ============ codebook transpose: cb[l][code][d] -> cbT[l][d][code] ============
__global__ __launch_bounds__(256) void k_tcb(const float* __restrict__ cb,
                                             float* __restrict__ cbT) {
  __shared__ __align__(16) float sh[16][272];
  const int tid = threadIdx.x;
  const int lvl = blockIdx.x >> 6;
  const int c0 = (blockIdx.x & 63) * 16;
  {
    const int cr = tid >> 4;
    const int l16 = tid & 15;
    const float4* p = reinterpret_cast<const float4*>(
        cb + ((size_t)lvl * KCODES + c0 + cr) * DIM + l16 * 16);
    #pragma unroll
    for (int j = 0; j < 4; ++j) {
      float4 v = p[j];
      sh[cr][l16 * 16 + 4 * j + 0] = v.x;
      sh[cr][l16 * 16 + 4 * j + 1] = v.y;
      sh[cr][l16 * 16 + 4 * j + 2] = v.z;
      sh[cr][l16 * 16 + 4 * j + 3] = v.w;
    }
  }
  __syncthreads();
  {
    float w[16];
    #pragma unroll
    for (int r = 0; r < 16; ++r) w[r] = sh[r][tid];
    float4* o = reinterpret_cast<float4*>(
        cbT + (size_t)lvl * (DIM * KCODES) + (size_t)tid * KCODES + c0);
    o[0] = make_float4(w[0], w[1], w[2], w[3]);
    o[1] = make_float4(w[4], w[5], w[6], w[7]);
    o[2] = make_float4(w[8], w[9], w[10], w[11]);
    o[3] = make_float4(w[12], w[13], w[14], w[15]);
  }
}

// ============ x -> residT (transpose) + rowsq ============
__global__ __launch_bounds__(256) void k_prep(const float* __restrict__ x,
                                              float* __restrict__ residT,
                                              float* __restrict__ rowsq) {
  __shared__ __align__(16) float sh[16][272];
  __shared__ float sred[256];
  const int tid = threadIdx.x;
  const int row0 = blockIdx.x * 16;
  const int rr = tid >> 4;
  const int l16 = tid & 15;
  float e = 0.f;
  {
    const float4* p = reinterpret_cast<const float4*>(
        x + (size_t)(row0 + rr) * DIM + l16 * 16);
    #pragma unroll
    for (int j = 0; j < 4; ++j) {
      float4 v = p[j];
      sh[rr][l16 * 16 + 4 * j + 0] = v.x;
      sh[rr][l16 * 16 + 4 * j + 1] = v.y;
      sh[rr][l16 * 16 + 4 * j + 2] = v.z;
      sh[rr][l16 * 16 + 4 * j + 3] = v.w;
      e += v.x * v.x + v.y * v.y + v.z * v.z + v.w * v.w;
    }
  }
  sred[tid] = e;
  __syncthreads();
  if (tid < 16) {
    float s = 0.f;
    #pragma unroll
    for (int k = 0; k < 16; ++k) s += sred[tid * 16 + k];
    rowsq[row0 + tid] = s;
  }
  {
    float w[16];
    #pragma unroll
    for (int r = 0; r < 16; ++r) w[r] = sh[r][tid];
    float4* o = reinterpret_cast<float4*>(residT + (size_t)tid * NROWS + row0);
    o[0] = make_float4(w[0], w[1], w[2], w[3]);
    o[1] = make_float4(w[4], w[5], w[6], w[7]);
    o[2] = make_float4(w[8], w[9], w[10], w[11]);
    o[3] = make_float4(w[12], w[13], w[14], w[15]);
  }
}

// ============ fused distance + argmin, one level ============
// 1024 blocks = 256 row-tiles (low bits) x 4 code-quarters (high bits; 256%8==0
// so all 4 quarters of a row-tile share an XCD). Block: 16 tx (codes) x 16 ty.
// Steady state per lane-d: 128 FMA + 2 ds_read_b128 (imm offsets) + 4 global
// b128 (one pointer += stride, imm offsets) + ~2 VALU. C register sets alternate
// (no copies). Distance FMA chain bit-identical to rounds 1-4.
__global__ __launch_bounds__(256, 2) void k_argmin(const float* __restrict__ residT,
                                                   const float* __restrict__ cbT,
                                                   const float* __restrict__ bv,
                                                   const float* __restrict__ rowsq,
                                                   unsigned long long* __restrict__ best) {
  __shared__ __align__(16) float Rt[2][DTILE * RTILE];  // 2 x 16 KB
  const int tid = threadIdx.x;
  const int tx = tid & 15;
  const int ty = tid >> 4;
  const int rt = blockIdx.x & 255;
  const int q = blockIdx.x >> 8;
  const int cbase = q * 256;
  const int row0 = rt * RTILE;

  float acc[8][16];
  #pragma unroll
  for (int i = 0; i < 8; ++i)
    #pragma unroll
    for (int j = 0; j < 16; ++j) acc[i][j] = 0.f;

  // ---- stage R tile 0 ----
  float4 sreg0, sreg1, sreg2, sreg3;
  const int f = tid * 4;
  {
    sreg0 = *reinterpret_cast<const float4*>(residT + (size_t)((f) >> 7) * NROWS + row0 + (f & 127));
    sreg1 = *reinterpret_cast<const float4*>(residT + (size_t)((f + 1024) >> 7) * NROWS + row0 + ((f + 1024) & 127));
    sreg2 = *reinterpret_cast<const float4*>(residT + (size_t)((f + 2048) >> 7) * NROWS + row0 + ((f + 2048) & 127));
    sreg3 = *reinterpret_cast<const float4*>(residT + (size_t)((f + 3072) >> 7) * NROWS + row0 + ((f + 3072) & 127));
    *reinterpret_cast<float4*>(&Rt[0][tid * 4])        = sreg0;
    *reinterpret_cast<float4*>(&Rt[0][tid * 4 + 1024]) = sreg1;
    *reinterpret_cast<float4*>(&Rt[0][tid * 4 + 2048]) = sreg2;
    *reinterpret_cast<float4*>(&Rt[0][tid * 4 + 3072]) = sreg3;
  }

  // ---- C pipeline prologue: load set A for d=0 ----
  const float* cptr = cbT + cbase + 4 * tx;  // advances by KCODES per d
  float4 ca0, ca1, ca2, ca3, cb0, cb1, cb2, cb3;
  ca0 = *reinterpret_cast<const float4*>(cptr);
  ca1 = *reinterpret_cast<const float4*>(cptr + 64);
  ca2 = *reinterpret_cast<const float4*>(cptr + 128);
  ca3 = *reinterpret_cast<const float4*>(cptr + 192);
  cptr += KCODES;

  __syncthreads();

#define FMASTEP(S0, S1, S2, S3, RPTR)                                   \
  {                                                                     \
    float4 r0_ = *reinterpret_cast<const float4*>(RPTR);                \
    float4 r1_ = *reinterpret_cast<const float4*>((RPTR) + 4);          \
    float rr8[8] = {r0_.x, r0_.y, r0_.z, r0_.w, r1_.x, r1_.y, r1_.z, r1_.w}; \
    float cc16[16] = {S0.x, S0.y, S0.z, S0.w, S1.x, S1.y, S1.z, S1.w,   \
                      S2.x, S2.y, S2.z, S2.w, S3.x, S3.y, S3.z, S3.w};  \
    _Pragma("unroll")                                                   \
    for (int i_ = 0; i_ < 8; ++i_)                                      \
      _Pragma("unroll")                                                 \
      for (int j_ = 0; j_ < 16; ++j_)                                   \
        acc[i_][j_] += rr8[i_] * cc16[j_];                              \
  }

  #pragma unroll 1
  for (int t = 0; t < DIM / DTILE; ++t) {
    // issue next R tile's global loads (consumed after inner loop)
    if (t + 1 < DIM / DTILE) {
      const size_t dB = (size_t)(t + 1) * DTILE;
      sreg0 = *reinterpret_cast<const float4*>(residT + (dB + ((f) >> 7)) * NROWS + row0 + (f & 127));
      sreg1 = *reinterpret_cast<const float4*>(residT + (dB + ((f + 1024) >> 7)) * NROWS + row0 + ((f + 1024) & 127));
      sreg2 = *reinterpret_cast<const float4*>(residT + (dB + ((f + 2048) >> 7)) * NROWS + row0 + ((f + 2048) & 127));
      sreg3 = *reinterpret_cast<const float4*>(residT + (dB + ((f + 3072) >> 7)) * NROWS + row0 + ((f + 3072) & 127));
    }
    const float* rb = &Rt[t & 1][ty * 8];
    #pragma unroll
    for (int h = 0; h < DTILE / 2; ++h) {
      // even d = t*32 + 2h: consume set A; load set B for d+1
      cb0 = *reinterpret_cast<const float4*>(cptr);
      cb1 = *reinterpret_cast<const float4*>(cptr + 64);
      cb2 = *reinterpret_cast<const float4*>(cptr + 128);
      cb3 = *reinterpret_cast<const float4*>(cptr + 192);
      cptr += KCODES;
      FMASTEP(ca0, ca1, ca2, ca3, rb + (2 * h) * RTILE);
      // odd d: consume set B; load set A for d+2 (last one lands in ws pad)
      ca0 = *reinterpret_cast<const float4*>(cptr);
      ca1 = *reinterpret_cast<const float4*>(cptr + 64);
      ca2 = *reinterpret_cast<const float4*>(cptr + 128);
      ca3 = *reinterpret_cast<const float4*>(cptr + 192);
      cptr += KCODES;
      FMASTEP(cb0, cb1, cb2, cb3, rb + (2 * h + 1) * RTILE);
    }
    if (t + 1 < DIM / DTILE) {
      __syncthreads();  // all waves done reading Rt[(t+1)&1]
      const int b = (t + 1) & 1;
      *reinterpret_cast<float4*>(&Rt[b][tid * 4])        = sreg0;
      *reinterpret_cast<float4*>(&Rt[b][tid * 4 + 1024]) = sreg1;
      *reinterpret_cast<float4*>(&Rt[b][tid * 4 + 2048]) = sreg2;
      *reinterpret_cast<float4*>(&Rt[b][tid * 4 + 3072]) = sreg3;
      __syncthreads();
    }
  }
#undef FMASTEP

  // epilogue: dd = fl(fl(A+B) - 2*dot); u64 (dist,idx) min over tx; atomicMin
  const float* bvq = bv + cbase;
  #pragma unroll
  for (int i = 0; i < 8; ++i) {
    const int row = row0 + ty * 8 + i;
    const float a = rowsq[row];
    unsigned long long u = ~0ull;
    #pragma unroll
    for (int j = 0; j < 4; ++j) {
      #pragma unroll
      for (int qq = 0; qq < 4; ++qq) {
        const int cl = 64 * j + 4 * tx + qq;
        float tt = a + bvq[cl];                     // fl(A + B)
        float d2 = tt - 2.0f * acc[i][4 * j + qq];  // one rounding
        unsigned long long pk =
            ((unsigned long long)__float_as_uint(d2) << 32) |
            (unsigned)(cbase + cl);
        u = (pk < u) ? pk : u;
      }
    }
    #pragma unroll
    for (int m = 1; m < 16; m <<= 1) {
      unsigned long long o = __shfl_xor(u, m);
      u = (o < u) ? o : u;
    }
    if (tx == 0) atomicMin(best + row, u);
  }
}

// ============ residual update (T layout) + quant accum + losses ============
__global__ __launch_bounds__(256) void k_update(float* __restrict__ residT,
                                                const float* __restrict__ cb,
                                                const unsigned long long* __restrict__ best,
                                                float* __restrict__ tq,
                                                float* __restrict__ fidx,
                                                float* __restrict__ part,
                                                float* __restrict__ rowsq,
                                                const float* __restrict__ x,
                                                int lvl) {
  __shared__ __align__(16) float sh[16][272];
  __shared__ float sred[256];
  const int tid = threadIdx.x;
  const int row0 = blockIdx.x * 16;

  {
    const float4* p = reinterpret_cast<const float4*>(residT + (size_t)tid * NROWS + row0);
    float4 a0 = p[0], a1 = p[1], a2 = p[2], a3 = p[3];
    sh[0][tid] = a0.x;  sh[1][tid] = a0.y;  sh[2][tid] = a0.z;  sh[3][tid] = a0.w;
    sh[4][tid] = a1.x;  sh[5][tid] = a1.y;  sh[6][tid] = a1.z;  sh[7][tid] = a1.w;
    sh[8][tid] = a2.x;  sh[9][tid] = a2.y;  sh[10][tid] = a2.z; sh[11][tid] = a2.w;
    sh[12][tid] = a3.x; sh[13][tid] = a3.y; sh[14][tid] = a3.z; sh[15][tid] = a3.w;
  }
  __syncthreads();

  const int rr = tid >> 4;
  const int l16 = tid & 15;
  const int row = row0 + rr;
  const int id = (int)(best[row] & 0xffffffffull);
  float nn[16];
  float e = 0.f;
  {
    const float4* cp = reinterpret_cast<const float4*>(cb + (size_t)id * DIM + l16 * 16);
    const size_t obase = (size_t)row * DIM + l16 * 16;
    float4* tp = reinterpret_cast<float4*>(tq + obase);
    const float4* xp = reinterpret_cast<const float4*>(x + obase);
    #pragma unroll
    for (int j = 0; j < 4; ++j) {
      float4 c = cp[j];
      float r0 = sh[rr][l16 * 16 + 4 * j + 0];
      float r1 = sh[rr][l16 * 16 + 4 * j + 1];
      float r2 = sh[rr][l16 * 16 + 4 * j + 2];
      float r3 = sh[rr][l16 * 16 + 4 * j + 3];
      float n0 = r0 - c.x, n1 = r1 - c.y, n2 = r2 - c.z, n3 = r3 - c.w;
      nn[4 * j + 0] = n0; nn[4 * j + 1] = n1; nn[4 * j + 2] = n2; nn[4 * j + 3] = n3;
      e += (n0 * n0 + n1 * n1) + (n2 * n2 + n3 * n3);
      float4 tv;
      if (lvl == 0) {
        tv = c;
      } else {
        tv = tp[j];
        tv.x += c.x; tv.y += c.y; tv.z += c.z; tv.w += c.w;
      }
      if (lvl == 3) {
        float4 xv = xp[j];
        tv.x = xv.x + (tv.x - xv.x); tv.y = xv.y + (tv.y - xv.y);
        tv.z = xv.z + (tv.z - xv.z); tv.w = xv.w + (tv.w - xv.w);
      }
      tp[j] = tv;
    }
  }
  sred[tid] = e;
  if (l16 == 0) fidx[row] = (float)id;
  __syncthreads();

  __shared__ float rsum[16];
  if (tid < 16) {
    float s = 0.f;
    #pragma unroll
    for (int k = 0; k < 16; ++k) s += sred[tid * 16 + k];
    rsum[tid] = s;
    if (lvl < 3) rowsq[row0 + tid] = s;
  }
  __syncthreads();
  if (tid == 0) {
    float p = 0.f;
    #pragma unroll
    for (int k = 0; k < 16; ++k) p += rsum[k];
    part[blockIdx.x] = p;
  }

  if (lvl < 3) {
    #pragma unroll
    for (int k = 0; k < 16; ++k) sh[rr][l16 * 16 + k] = nn[k];
    __syncthreads();
    float w[16];
    #pragma unroll
    for (int r = 0; r < 16; ++r) w[r] = sh[r][tid];
    float4* o = reinterpret_cast<float4*>(residT + (size_t)tid * NROWS + row0);
    o[0] = make_float4(w[0], w[1], w[2], w[3]);
    o[1] = make_float4(w[4], w[5], w[6], w[7]);
    o[2] = make_float4(w[8], w[9], w[10], w[11]);
    o[3] = make_float4(w[12], w[13], w[14], w[15]);
  }
}

// ============ loss finalize ============
__global__ __launch_bounds__(256) void k_loss(const float* __restrict__ part,
                                              float* __restrict__ out) {
  __shared__ float s[256];
  const int tid = threadIdx.x;
  float means[4];
  for (int l = 0; l < 4; ++l) {
    float sum = 0.f;
    for (int i = tid; i < 2048; i += 256) sum += part[l * 2048 + i];
    s[tid] = sum;
    __syncthreads();
    for (int st = 128; st > 0; st >>= 1) {
      if (tid < st) s[tid] += s[tid + st];
      __syncthreads();
    }
    means[l] = s[0] * (1.0f / 8388608.0f);  // /(N*D), exact pow2
    __syncthreads();
  }
  if (tid == 0) {
    float t = ((means[0] + means[1]) + means[2]) + means[3];
    float loss = t * 0.25f;
    out[0] = loss;
    out[1] = loss;
  }
}

extern "C" void kernel_launch(void* const* d_in, const int* in_sizes, int n_in,
                              void* d_out, int out_size, void* d_ws, size_t ws_size,
                              hipStream_t stream) {
  const float* x  = (const float*)d_in[0];
  const float* cb = (const float*)d_in[1];
  float* out = (float*)d_out;
  float* ws  = (float*)d_ws;

  // ws layout (float units)
  float* residT = ws;                                   // 8388608
  unsigned long long* best4 = (unsigned long long*)(ws + 8388608);  // 131072 u64
  float* part  = ws + 8388608 + 262144;                 // 4*2048
  float* bv    = ws + 8388608 + 262144 + 8192;          // 4096
  float* rowsq = ws + 8388608 + 262144 + 8192 + 4096;   // 32768
  float* cbT   = ws + 8388608 + 262144 + 8192 + 4096 + 32768;  // 4*262144 + 1024 pad
  // pad: one phantom C-load at d=256 for level 3 lands in [cbT+1048576, +1024)

  float* tq      = out;                    // total_quant accumulates in d_out
  float* lossout = out + 8388608;
  float* fidx    = out + 8388610;

  hipMemsetAsync(best4, 0xFF, (size_t)NLEV * NROWS * 8, stream);
  k_bnorm<<<16, 256, 0, stream>>>(cb, bv);
  k_tcb<<<256, 256, 0, stream>>>(cb, cbT);
  k_prep<<<2048, 256, 0, stream>>>(x, residT, rowsq);

  for (int l = 0; l < NLEV; ++l) {
    const float* cbl  = cb  + (size_t)l * KCODES * DIM;
    const float* cbTl = cbT + (size_t)l * KCODES * DIM;
    k_argmin<<<1024, 256, 0, stream>>>(residT, cbTl, bv + l * KCODES, rowsq,
                                       best4 + (size_t)l * NROWS);
    k_update<<<2048, 256, 0, stream>>>(residT, cbl, best4 + (size_t)l * NROWS,
                                       tq, fidx + (size_t)l * NROWS,
                                       part + l * 2048, rowsq, x, l);
  }

  k_loss<<<1, 256, 0, stream>>>(part, lossout);
}

// Round 6
// 1024.021 us; speedup vs baseline: 12.8880x; 12.8880x over previous
//
#include <hip/hip_runtime.h>

#define NROWS 32768   // B*T = 16*2048
#define DIM 256
#define KCODES 1024
#define NLEV 4

typedef float f32x16 __attribute__((ext_vector_type(16)));

// ============ codebook squared norms (bit-identical to passing rounds) ============
__global__ __launch_bounds__(256) void k_bnorm(const float* __restrict__ cb,
                                               float* __restrict__ bv) {
  int r = blockIdx.x * blockDim.x + threadIdx.x;  // 0..4095
  if (r >= NLEV * KCODES) return;
  const float4* p = reinterpret_cast<const float4*>(cb + (size_t)r * DIM);
  float s0 = 0.f, s1 = 0.f, s2 = 0.f, s3 = 0.f;
  for (int g = 0; g < DIM / 4; ++g) {
    float4 v = p[g];
    s0 += v.x * v.x; s1 += v.y * v.y; s2 += v.z * v.z; s3 += v.w * v.w;
  }
  bv[r] = (s0 + s1) + (s2 + s3);
}

// ============ codebook transpose: cb[l][code][d] -> cbT[l][d][code] ============
__global__ __launch_bounds__(256) void k_tcb(const float* __restrict__ cb,
                                             float* __restrict__ cbT) {
  __shared__ __align__(16) float sh[16][272];
  const int tid = threadIdx.x;
  const int lvl = blockIdx.x >> 6;
  const int c0 = (blockIdx.x & 63) * 16;
  {
    const int cr = tid >> 4;
    const int l16 = tid & 15;
    const float4* p = reinterpret_cast<const float4*>(
        cb + ((size_t)lvl * KCODES + c0 + cr) * DIM + l16 * 16);
    #pragma unroll
    for (int j = 0; j < 4; ++j) {
      float4 v = p[j];
      sh[cr][l16 * 16 + 4 * j + 0] = v.x;
      sh[cr][l16 * 16 + 4 * j + 1] = v.y;
      sh[cr][l16 * 16 + 4 * j + 2] = v.z;
      sh[cr][l16 * 16 + 4 * j + 3] = v.w;
    }
  }
  __syncthreads();
  {
    float w[16];
    #pragma unroll
    for (int r = 0; r < 16; ++r) w[r] = sh[r][tid];
    float4* o = reinterpret_cast<float4*>(
        cbT + (size_t)lvl * (DIM * KCODES) + (size_t)tid * KCODES + c0);
    o[0] = make_float4(w[0], w[1], w[2], w[3]);
    o[1] = make_float4(w[4], w[5], w[6], w[7]);
    o[2] = make_float4(w[8], w[9], w[10], w[11]);
    o[3] = make_float4(w[12], w[13], w[14], w[15]);
  }
}

// ============ x -> residT (transpose) + rowsq ============
__global__ __launch_bounds__(256) void k_prep(const float* __restrict__ x,
                                              float* __restrict__ residT,
                                              float* __restrict__ rowsq) {
  __shared__ __align__(16) float sh[16][272];
  __shared__ float sred[256];
  const int tid = threadIdx.x;
  const int row0 = blockIdx.x * 16;
  const int rr = tid >> 4;
  const int l16 = tid & 15;
  float e = 0.f;
  {
    const float4* p = reinterpret_cast<const float4*>(
        x + (size_t)(row0 + rr) * DIM + l16 * 16);
    #pragma unroll
    for (int j = 0; j < 4; ++j) {
      float4 v = p[j];
      sh[rr][l16 * 16 + 4 * j + 0] = v.x;
      sh[rr][l16 * 16 + 4 * j + 1] = v.y;
      sh[rr][l16 * 16 + 4 * j + 2] = v.z;
      sh[rr][l16 * 16 + 4 * j + 3] = v.w;
      e += v.x * v.x + v.y * v.y + v.z * v.z + v.w * v.w;
    }
  }
  sred[tid] = e;
  __syncthreads();
  if (tid < 16) {
    float s = 0.f;
    #pragma unroll
    for (int k = 0; k < 16; ++k) s += sred[tid * 16 + k];
    rowsq[row0 + tid] = s;
  }
  {
    float w[16];
    #pragma unroll
    for (int r = 0; r < 16; ++r) w[r] = sh[r][tid];
    float4* o = reinterpret_cast<float4*>(residT + (size_t)tid * NROWS + row0);
    o[0] = make_float4(w[0], w[1], w[2], w[3]);
    o[1] = make_float4(w[4], w[5], w[6], w[7]);
    o[2] = make_float4(w[8], w[9], w[10], w[11]);
    o[3] = make_float4(w[12], w[13], w[14], w[15]);
  }
}

// ============ fused distance + argmin, one level ============
// 2048 blocks = 512 row-tiles (low bits, 64 rows) x 4 code-quarters (high bits;
// 512%8==0 -> same rows land on same XCD across quarters). Block: 4 waves; each
// wave owns 16 rows x 256 codes (lane = 4 codes). R arrives via the SCALAR pipe:
// inline-asm s_load_dwordx16 (wave-uniform base, imm offsets for 4 d's), so the
// VALU stream is ~96% pure v_fmac (64 FMA + 1 C-load per lane-d). No LDS, no
// barriers. FMA chain (ascending d) and epilogue bit-identical to rounds 1-5.
__global__ __launch_bounds__(256) void k_argmin(const float* __restrict__ residT,
                                                const float* __restrict__ cbT,
                                                const float* __restrict__ bv,
                                                const float* __restrict__ rowsq,
                                                unsigned long long* __restrict__ best) {
  const int tid = threadIdx.x;
  const int lane = tid & 63;
  const int wid = tid >> 6;
  const int rt = blockIdx.x & 511;
  const int q = blockIdx.x >> 9;
  const int cbase = q * 256;
  const int rowbase = rt * 64 + wid * 16;

  // wave-uniform scalar base: &residT[0][rowbase]
  const float* rp0 = residT + rowbase;
  unsigned blo = __builtin_amdgcn_readfirstlane((unsigned)(uintptr_t)rp0);
  unsigned bhi = __builtin_amdgcn_readfirstlane((unsigned)((uintptr_t)rp0 >> 32));
  unsigned long long sbase = ((unsigned long long)bhi << 32) | blo;

  const float* cp = cbT + cbase + 4 * lane;  // per-lane C pointer, +KCODES per d

  float acc[16][4];
  #pragma unroll
  for (int r = 0; r < 16; ++r)
    #pragma unroll
    for (int j = 0; j < 4; ++j) acc[r][j] = 0.f;

  #pragma unroll 2
  for (int g = 0; g < DIM / 4; ++g) {
    // C for the 4 d's of this group (coalesced 1 KB/wave-d, L2-resident panel)
    float4 c0 = *reinterpret_cast<const float4*>(cp);
    float4 c1 = *reinterpret_cast<const float4*>(cp + KCODES);
    float4 c2 = *reinterpret_cast<const float4*>(cp + 2 * KCODES);
    float4 c3 = *reinterpret_cast<const float4*>(cp + 3 * KCODES);
    cp += 4 * KCODES;

    // R rows rowbase..rowbase+15 for d = 4g..4g+3 via SMEM.
    // imm offsets: NROWS*4 = 0x20000 bytes per d.
    f32x16 r0, r1, r2, r3;
    asm volatile(
        "s_load_dwordx16 %0, %4, 0x0\n\t"
        "s_load_dwordx16 %1, %4, 0x20000\n\t"
        "s_load_dwordx16 %2, %4, 0x40000\n\t"
        "s_load_dwordx16 %3, %4, 0x60000\n\t"
        "s_waitcnt lgkmcnt(0)"
        : "=&s"(r0), "=&s"(r1), "=&s"(r2), "=&s"(r3)
        : "s"(sbase));
    sbase += 0x80000ull;  // 4 d * 128 KB

    #pragma unroll
    for (int r = 0; r < 16; ++r) {
      acc[r][0] += r0[r] * c0.x; acc[r][1] += r0[r] * c0.y;
      acc[r][2] += r0[r] * c0.z; acc[r][3] += r0[r] * c0.w;
    }
    #pragma unroll
    for (int r = 0; r < 16; ++r) {
      acc[r][0] += r1[r] * c1.x; acc[r][1] += r1[r] * c1.y;
      acc[r][2] += r1[r] * c1.z; acc[r][3] += r1[r] * c1.w;
    }
    #pragma unroll
    for (int r = 0; r < 16; ++r) {
      acc[r][0] += r2[r] * c2.x; acc[r][1] += r2[r] * c2.y;
      acc[r][2] += r2[r] * c2.z; acc[r][3] += r2[r] * c2.w;
    }
    #pragma unroll
    for (int r = 0; r < 16; ++r) {
      acc[r][0] += r3[r] * c3.x; acc[r][1] += r3[r] * c3.y;
      acc[r][2] += r3[r] * c3.z; acc[r][3] += r3[r] * c3.w;
    }
  }

  // epilogue: dd = fl(fl(A+B) - 2*dot); u64 (dist,idx) min over 64 lanes
  const float4 bvv = *reinterpret_cast<const float4*>(bv + cbase + 4 * lane);
  const int code0 = cbase + 4 * lane;
  #pragma unroll
  for (int r = 0; r < 16; ++r) {
    const float a = rowsq[rowbase + r];
    float t0 = a + bvv.x; float d0 = t0 - 2.0f * acc[r][0];
    float t1 = a + bvv.y; float d1 = t1 - 2.0f * acc[r][1];
    float t2 = a + bvv.z; float d2 = t2 - 2.0f * acc[r][2];
    float t3 = a + bvv.w; float d3 = t3 - 2.0f * acc[r][3];
    unsigned long long u0 = ((unsigned long long)__float_as_uint(d0) << 32) | (unsigned)(code0 + 0);
    unsigned long long u1 = ((unsigned long long)__float_as_uint(d1) << 32) | (unsigned)(code0 + 1);
    unsigned long long u2 = ((unsigned long long)__float_as_uint(d2) << 32) | (unsigned)(code0 + 2);
    unsigned long long u3 = ((unsigned long long)__float_as_uint(d3) << 32) | (unsigned)(code0 + 3);
    unsigned long long u = u0 < u1 ? u0 : u1;
    u = u2 < u ? u2 : u;
    u = u3 < u ? u3 : u;
    #pragma unroll
    for (int m = 1; m < 64; m <<= 1) {
      unsigned long long o = __shfl_xor(u, m);
      u = (o < u) ? o : u;
    }
    if (lane == 0) atomicMin(best + rowbase + r, u);
  }
}

// ============ residual update (T layout) + quant accum + losses ============
__global__ __launch_bounds__(256) void k_update(float* __restrict__ residT,
                                                const float* __restrict__ cb,
                                                const unsigned long long* __restrict__ best,
                                                float* __restrict__ tq,
                                                float* __restrict__ fidx,
                                                float* __restrict__ part,
                                                float* __restrict__ rowsq,
                                                const float* __restrict__ x,
                                                int lvl) {
  __shared__ __align__(16) float sh[16][272];
  __shared__ float sred[256];
  const int tid = threadIdx.x;
  const int row0 = blockIdx.x * 16;

  {
    const float4* p = reinterpret_cast<const float4*>(residT + (size_t)tid * NROWS + row0);
    float4 a0 = p[0], a1 = p[1], a2 = p[2], a3 = p[3];
    sh[0][tid] = a0.x;  sh[1][tid] = a0.y;  sh[2][tid] = a0.z;  sh[3][tid] = a0.w;
    sh[4][tid] = a1.x;  sh[5][tid] = a1.y;  sh[6][tid] = a1.z;  sh[7][tid] = a1.w;
    sh[8][tid] = a2.x;  sh[9][tid] = a2.y;  sh[10][tid] = a2.z; sh[11][tid] = a2.w;
    sh[12][tid] = a3.x; sh[13][tid] = a3.y; sh[14][tid] = a3.z; sh[15][tid] = a3.w;
  }
  __syncthreads();

  const int rr = tid >> 4;
  const int l16 = tid & 15;
  const int row = row0 + rr;
  const int id = (int)(best[row] & 0xffffffffull);
  float nn[16];
  float e = 0.f;
  {
    const float4* cp = reinterpret_cast<const float4*>(cb + (size_t)id * DIM + l16 * 16);
    const size_t obase = (size_t)row * DIM + l16 * 16;
    float4* tp = reinterpret_cast<float4*>(tq + obase);
    const float4* xp = reinterpret_cast<const float4*>(x + obase);
    #pragma unroll
    for (int j = 0; j < 4; ++j) {
      float4 c = cp[j];
      float r0 = sh[rr][l16 * 16 + 4 * j + 0];
      float r1 = sh[rr][l16 * 16 + 4 * j + 1];
      float r2 = sh[rr][l16 * 16 + 4 * j + 2];
      float r3 = sh[rr][l16 * 16 + 4 * j + 3];
      float n0 = r0 - c.x, n1 = r1 - c.y, n2 = r2 - c.z, n3 = r3 - c.w;
      nn[4 * j + 0] = n0; nn[4 * j + 1] = n1; nn[4 * j + 2] = n2; nn[4 * j + 3] = n3;
      e += (n0 * n0 + n1 * n1) + (n2 * n2 + n3 * n3);
      float4 tv;
      if (lvl == 0) {
        tv = c;
      } else {
        tv = tp[j];
        tv.x += c.x; tv.y += c.y; tv.z += c.z; tv.w += c.w;
      }
      if (lvl == 3) {
        float4 xv = xp[j];
        tv.x = xv.x + (tv.x - xv.x); tv.y = xv.y + (tv.y - xv.y);
        tv.z = xv.z + (tv.z - xv.z); tv.w = xv.w + (tv.w - xv.w);
      }
      tp[j] = tv;
    }
  }
  sred[tid] = e;
  if (l16 == 0) fidx[row] = (float)id;
  __syncthreads();

  __shared__ float rsum[16];
  if (tid < 16) {
    float s = 0.f;
    #pragma unroll
    for (int k = 0; k < 16; ++k) s += sred[tid * 16 + k];
    rsum[tid] = s;
    if (lvl < 3) rowsq[row0 + tid] = s;
  }
  __syncthreads();
  if (tid == 0) {
    float p = 0.f;
    #pragma unroll
    for (int k = 0; k < 16; ++k) p += rsum[k];
    part[blockIdx.x] = p;
  }

  if (lvl < 3) {
    #pragma unroll
    for (int k = 0; k < 16; ++k) sh[rr][l16 * 16 + k] = nn[k];
    __syncthreads();
    float w[16];
    #pragma unroll
    for (int r = 0; r < 16; ++r) w[r] = sh[r][tid];
    float4* o = reinterpret_cast<float4*>(residT + (size_t)tid * NROWS + row0);
    o[0] = make_float4(w[0], w[1], w[2], w[3]);
    o[1] = make_float4(w[4], w[5], w[6], w[7]);
    o[2] = make_float4(w[8], w[9], w[10], w[11]);
    o[3] = make_float4(w[12], w[13], w[14], w[15]);
  }
}

// ============ loss finalize ============
__global__ __launch_bounds__(256) void k_loss(const float* __restrict__ part,
                                              float* __restrict__ out) {
  __shared__ float s[256];
  const int tid = threadIdx.x;
  float means[4];
  for (int l = 0; l < 4; ++l) {
    float sum = 0.f;
    for (int i = tid; i < 2048; i += 256) sum += part[l * 2048 + i];
    s[tid] = sum;
    __syncthreads();
    for (int st = 128; st > 0; st >>= 1) {
      if (tid < st) s[tid] += s[tid + st];
      __syncthreads();
    }
    means[l] = s[0] * (1.0f / 8388608.0f);  // /(N*D), exact pow2
    __syncthreads();
  }
  if (tid == 0) {
    float t = ((means[0] + means[1]) + means[2]) + means[3];
    float loss = t * 0.25f;
    out[0] = loss;
    out[1] = loss;
  }
}

extern "C" void kernel_launch(void* const* d_in, const int* in_sizes, int n_in,
                              void* d_out, int out_size, void* d_ws, size_t ws_size,
                              hipStream_t stream) {
  const float* x  = (const float*)d_in[0];
  const float* cb = (const float*)d_in[1];
  float* out = (float*)d_out;
  float* ws  = (float*)d_ws;

  // ws layout (float units)
  float* residT = ws;                                   // 8388608
  unsigned long long* best4 = (unsigned long long*)(ws + 8388608);  // 131072 u64
  float* part  = ws + 8388608 + 262144;                 // 4*2048
  float* bv    = ws + 8388608 + 262144 + 8192;          // 4096
  float* rowsq = ws + 8388608 + 262144 + 8192 + 4096;   // 32768
  float* cbT   = ws + 8388608 + 262144 + 8192 + 4096 + 32768;  // 4*262144

  float* tq      = out;                    // total_quant accumulates in d_out
  float* lossout = out + 8388608;
  float* fidx    = out + 8388610;

  hipMemsetAsync(best4, 0xFF, (size_t)NLEV * NROWS * 8, stream);
  k_bnorm<<<16, 256, 0, stream>>>(cb, bv);
  k_tcb<<<256, 256, 0, stream>>>(cb, cbT);
  k_prep<<<2048, 256, 0, stream>>>(x, residT, rowsq);

  for (int l = 0; l < NLEV; ++l) {
    const float* cbl  = cb  + (size_t)l * KCODES * DIM;
    const float* cbTl = cbT + (size_t)l * KCODES * DIM;
    k_argmin<<<2048, 256, 0, stream>>>(residT, cbTl, bv + l * KCODES, rowsq,
                                       best4 + (size_t)l * NROWS);
    k_update<<<2048, 256, 0, stream>>>(residT, cbl, best4 + (size_t)l * NROWS,
                                       tq, fidx + (size_t)l * NROWS,
                                       part + l * 2048, rowsq, x, l);
  }

  k_loss<<<1, 256, 0, stream>>>(part, lossout);
}

// Round 7
// 944.379 us; speedup vs baseline: 13.9749x; 1.0843x over previous
//
#include <hip/hip_runtime.h>

#define NROWS 32768   // B*T = 16*2048
#define DIM 256
#define KCODES 1024
#define NLEV 4

typedef float f32x16 __attribute__((ext_vector_type(16)));
typedef float f32x2  __attribute__((ext_vector_type(2)));

// ============ codebook squared norms (bit-identical to passing rounds) ============
__global__ __launch_bounds__(256) void k_bnorm(const float* __restrict__ cb,
                                               float* __restrict__ bv) {
  int r = blockIdx.x * blockDim.x + threadIdx.x;  // 0..4095
  if (r >= NLEV * KCODES) return;
  const float4* p = reinterpret_cast<const float4*>(cb + (size_t)r * DIM);
  float s0 = 0.f, s1 = 0.f, s2 = 0.f, s3 = 0.f;
  for (int g = 0; g < DIM / 4; ++g) {
    float4 v = p[g];
    s0 += v.x * v.x; s1 += v.y * v.y; s2 += v.z * v.z; s3 += v.w * v.w;
  }
  bv[r] = (s0 + s1) + (s2 + s3);
}

// ============ codebook transpose: cb[l][code][d] -> cbT[l][d][code] ============
__global__ __launch_bounds__(256) void k_tcb(const float* __restrict__ cb,
                                             float* __restrict__ cbT) {
  __shared__ __align__(16) float sh[16][272];
  const int tid = threadIdx.x;
  const int lvl = blockIdx.x >> 6;
  const int c0 = (blockIdx.x & 63) * 16;
  {
    const int cr = tid >> 4;
    const int l16 = tid & 15;
    const float4* p = reinterpret_cast<const float4*>(
        cb + ((size_t)lvl * KCODES + c0 + cr) * DIM + l16 * 16);
    #pragma unroll
    for (int j = 0; j < 4; ++j) {
      float4 v = p[j];
      sh[cr][l16 * 16 + 4 * j + 0] = v.x;
      sh[cr][l16 * 16 + 4 * j + 1] = v.y;
      sh[cr][l16 * 16 + 4 * j + 2] = v.z;
      sh[cr][l16 * 16 + 4 * j + 3] = v.w;
    }
  }
  __syncthreads();
  {
    float w[16];
    #pragma unroll
    for (int r = 0; r < 16; ++r) w[r] = sh[r][tid];
    float4* o = reinterpret_cast<float4*>(
        cbT + (size_t)lvl * (DIM * KCODES) + (size_t)tid * KCODES + c0);
    o[0] = make_float4(w[0], w[1], w[2], w[3]);
    o[1] = make_float4(w[4], w[5], w[6], w[7]);
    o[2] = make_float4(w[8], w[9], w[10], w[11]);
    o[3] = make_float4(w[12], w[13], w[14], w[15]);
  }
}

// ============ x -> residT (transpose) + rowsq ============
__global__ __launch_bounds__(256) void k_prep(const float* __restrict__ x,
                                              float* __restrict__ residT,
                                              float* __restrict__ rowsq) {
  __shared__ __align__(16) float sh[16][272];
  __shared__ float sred[256];
  const int tid = threadIdx.x;
  const int row0 = blockIdx.x * 16;
  const int rr = tid >> 4;
  const int l16 = tid & 15;
  float e = 0.f;
  {
    const float4* p = reinterpret_cast<const float4*>(
        x + (size_t)(row0 + rr) * DIM + l16 * 16);
    #pragma unroll
    for (int j = 0; j < 4; ++j) {
      float4 v = p[j];
      sh[rr][l16 * 16 + 4 * j + 0] = v.x;
      sh[rr][l16 * 16 + 4 * j + 1] = v.y;
      sh[rr][l16 * 16 + 4 * j + 2] = v.z;
      sh[rr][l16 * 16 + 4 * j + 3] = v.w;
      e += v.x * v.x + v.y * v.y + v.z * v.z + v.w * v.w;
    }
  }
  sred[tid] = e;
  __syncthreads();
  if (tid < 16) {
    float s = 0.f;
    #pragma unroll
    for (int k = 0; k < 16; ++k) s += sred[tid * 16 + k];
    rowsq[row0 + tid] = s;
  }
  {
    float w[16];
    #pragma unroll
    for (int r = 0; r < 16; ++r) w[r] = sh[r][tid];
    float4* o = reinterpret_cast<float4*>(residT + (size_t)tid * NROWS + row0);
    o[0] = make_float4(w[0], w[1], w[2], w[3]);
    o[1] = make_float4(w[4], w[5], w[6], w[7]);
    o[2] = make_float4(w[8], w[9], w[10], w[11]);
    o[3] = make_float4(w[12], w[13], w[14], w[15]);
  }
}

// pk helpers: D.lo = S0.lo*S1.sel+S2.lo ; D.hi = S0.hi*S1.sel+S2.hi
// PK_LO broadcasts S1.lo to both halves; PK_HI broadcasts S1.hi.
#define PK_LO(ACC, RP, CP)                                                     \
  asm volatile("v_pk_fma_f32 %0, %1, %2, %0 op_sel:[0,0,0] op_sel_hi:[1,0,1]"  \
               : "+v"(ACC) : "s"(RP), "v"(CP))
#define PK_HI(ACC, RP, CP)                                                     \
  asm volatile("v_pk_fma_f32 %0, %1, %2, %0 op_sel:[0,1,0] op_sel_hi:[1,1,1]"  \
               : "+v"(ACC) : "s"(RP), "v"(CP))

// one d: 8 row-pairs x 4 codes = 32 pk_fma (rows from SGPR pairs, codes from C4)
#define PKD(R16, C4)                                              \
  do {                                                            \
    f32x2 c01_, c23_;                                             \
    c01_[0] = (C4).x; c01_[1] = (C4).y;                           \
    c23_[0] = (C4).z; c23_[1] = (C4).w;                           \
    _Pragma("unroll")                                             \
    for (int k_ = 0; k_ < 8; ++k_) {                              \
      f32x2 rp_;                                                  \
      rp_[0] = (R16)[2 * k_]; rp_[1] = (R16)[2 * k_ + 1];         \
      PK_LO(acc2[k_][0], rp_, c01_);                              \
      PK_HI(acc2[k_][1], rp_, c01_);                              \
      PK_LO(acc2[k_][2], rp_, c23_);                              \
      PK_HI(acc2[k_][3], rp_, c23_);                              \
    }                                                             \
  } while (0)

#define ISSUE_R(R0, R1, BASE)                                          \
  asm volatile("s_load_dwordx16 %0, %2, 0x0\n\t"                       \
               "s_load_dwordx16 %1, %2, 0x20000"                       \
               : "=&s"(R0), "=&s"(R1) : "s"(BASE))

#define WAIT_R(R0, R1)                                                 \
  asm volatile("s_waitcnt lgkmcnt(0)" : "+s"(R0), "+s"(R1));           \
  __builtin_amdgcn_sched_barrier(0)

// ============ fused distance + argmin, one level ============
// 2048 blocks = 512 row-tiles x 4 code-quarters. Wave = 16 rows x 256 codes
// (lane = 4 codes). R via scalar pipe (s_load_dwordx16, double-buffered 2-d
// batches, wait(g)->issue(g+1)->compute(g)); C via per-lane float4, prefetched
// one batch ahead. FMA = v_pk_fma_f32 over row-pairs: each component is the
// same fused-FMA ascending-d chain as rounds 1-6 -> distances bit-identical.
__global__ __launch_bounds__(256) void k_argmin(const float* __restrict__ residT,
                                                const float* __restrict__ cbT,
                                                const float* __restrict__ bv,
                                                const float* __restrict__ rowsq,
                                                unsigned long long* __restrict__ best) {
  const int tid = threadIdx.x;
  const int lane = tid & 63;
  const int wid = tid >> 6;
  const int rt = blockIdx.x & 511;
  const int q = blockIdx.x >> 9;
  const int cbase = q * 256;
  const int rowbase = rt * 64 + wid * 16;

  // wave-uniform scalar base: &residT[0][rowbase]
  const float* rp0 = residT + rowbase;
  unsigned blo = __builtin_amdgcn_readfirstlane((unsigned)(uintptr_t)rp0);
  unsigned bhi = __builtin_amdgcn_readfirstlane((unsigned)((uintptr_t)rp0 >> 32));
  unsigned long long sbase = ((unsigned long long)bhi << 32) | blo;

  f32x2 acc2[8][4];
  #pragma unroll
  for (int k = 0; k < 8; ++k)
    #pragma unroll
    for (int j = 0; j < 4; ++j) { acc2[k][j][0] = 0.f; acc2[k][j][1] = 0.f; }

  f32x16 rA0, rA1, rB0, rB1;
  // prologue: issue R batch 0 (d=0,1), load C for d=0,1
  ISSUE_R(rA0, rA1, sbase);
  sbase += 0x40000ull;  // 2 d * 128 KB
  const float4* cptr = reinterpret_cast<const float4*>(cbT + cbase) + lane;
  float4 cA0 = cptr[0];
  float4 cA1 = cptr[256];
  cptr += 512;
  float4 cB0, cB1;

  #pragma unroll 1
  for (int i = 0; i < 64; ++i) {
    // even batch: consume A (d=4i,4i+1); issue B (d=4i+2,4i+3)
    WAIT_R(rA0, rA1);
    ISSUE_R(rB0, rB1, sbase);
    sbase += 0x40000ull;
    cB0 = cptr[0];
    cB1 = cptr[256];
    cptr += 512;
    PKD(rA0, cA0);
    PKD(rA1, cA1);
    // odd batch: consume B; issue A for next iteration (d=4i+4,4i+5)
    WAIT_R(rB0, rB1);
    if (i < 63) {
      ISSUE_R(rA0, rA1, sbase);
      sbase += 0x40000ull;
      cA0 = cptr[0];
      cA1 = cptr[256];
      cptr += 512;
    }
    PKD(rB0, cB0);
    PKD(rB1, cB1);
  }

  // epilogue: dd = fl(fl(A+B) - 2*dot); u64 (dist,idx) min over 64 lanes.
  // acc2[k][j][c] = dot(row 2k+c, code 4*lane+j) — identical values/order.
  const float4 bvv = *reinterpret_cast<const float4*>(bv + cbase + 4 * lane);
  const int code0 = cbase + 4 * lane;
  #pragma unroll
  for (int r = 0; r < 16; ++r) {
    const int k = r >> 1;
    const int c = r & 1;
    const float a = rowsq[rowbase + r];
    float t0 = a + bvv.x; float d0 = t0 - 2.0f * acc2[k][0][c];
    float t1 = a + bvv.y; float d1 = t1 - 2.0f * acc2[k][1][c];
    float t2 = a + bvv.z; float d2 = t2 - 2.0f * acc2[k][2][c];
    float t3 = a + bvv.w; float d3 = t3 - 2.0f * acc2[k][3][c];
    unsigned long long u0 = ((unsigned long long)__float_as_uint(d0) << 32) | (unsigned)(code0 + 0);
    unsigned long long u1 = ((unsigned long long)__float_as_uint(d1) << 32) | (unsigned)(code0 + 1);
    unsigned long long u2 = ((unsigned long long)__float_as_uint(d2) << 32) | (unsigned)(code0 + 2);
    unsigned long long u3 = ((unsigned long long)__float_as_uint(d3) << 32) | (unsigned)(code0 + 3);
    unsigned long long u = u0 < u1 ? u0 : u1;
    u = u2 < u ? u2 : u;
    u = u3 < u ? u3 : u;
    #pragma unroll
    for (int m = 1; m < 64; m <<= 1) {
      unsigned long long o = __shfl_xor(u, m);
      u = (o < u) ? o : u;
    }
    if (lane == 0) atomicMin(best + rowbase + r, u);
  }
}

// ============ residual update (T layout) + quant accum + losses ============
__global__ __launch_bounds__(256) void k_update(float* __restrict__ residT,
                                                const float* __restrict__ cb,
                                                const unsigned long long* __restrict__ best,
                                                float* __restrict__ tq,
                                                float* __restrict__ fidx,
                                                float* __restrict__ part,
                                                float* __restrict__ rowsq,
                                                const float* __restrict__ x,
                                                int lvl) {
  __shared__ __align__(16) float sh[16][272];
  __shared__ float sred[256];
  const int tid = threadIdx.x;
  const int row0 = blockIdx.x * 16;

  {
    const float4* p = reinterpret_cast<const float4*>(residT + (size_t)tid * NROWS + row0);
    float4 a0 = p[0], a1 = p[1], a2 = p[2], a3 = p[3];
    sh[0][tid] = a0.x;  sh[1][tid] = a0.y;  sh[2][tid] = a0.z;  sh[3][tid] = a0.w;
    sh[4][tid] = a1.x;  sh[5][tid] = a1.y;  sh[6][tid] = a1.z;  sh[7][tid] = a1.w;
    sh[8][tid] = a2.x;  sh[9][tid] = a2.y;  sh[10][tid] = a2.z; sh[11][tid] = a2.w;
    sh[12][tid] = a3.x; sh[13][tid] = a3.y; sh[14][tid] = a3.z; sh[15][tid] = a3.w;
  }
  __syncthreads();

  const int rr = tid >> 4;
  const int l16 = tid & 15;
  const int row = row0 + rr;
  const int id = (int)(best[row] & 0xffffffffull);
  float nn[16];
  float e = 0.f;
  {
    const float4* cp = reinterpret_cast<const float4*>(cb + (size_t)id * DIM + l16 * 16);
    const size_t obase = (size_t)row * DIM + l16 * 16;
    float4* tp = reinterpret_cast<float4*>(tq + obase);
    const float4* xp = reinterpret_cast<const float4*>(x + obase);
    #pragma unroll
    for (int j = 0; j < 4; ++j) {
      float4 c = cp[j];
      float r0 = sh[rr][l16 * 16 + 4 * j + 0];
      float r1 = sh[rr][l16 * 16 + 4 * j + 1];
      float r2 = sh[rr][l16 * 16 + 4 * j + 2];
      float r3 = sh[rr][l16 * 16 + 4 * j + 3];
      float n0 = r0 - c.x, n1 = r1 - c.y, n2 = r2 - c.z, n3 = r3 - c.w;
      nn[4 * j + 0] = n0; nn[4 * j + 1] = n1; nn[4 * j + 2] = n2; nn[4 * j + 3] = n3;
      e += (n0 * n0 + n1 * n1) + (n2 * n2 + n3 * n3);
      float4 tv;
      if (lvl == 0) {
        tv = c;
      } else {
        tv = tp[j];
        tv.x += c.x; tv.y += c.y; tv.z += c.z; tv.w += c.w;
      }
      if (lvl == 3) {
        float4 xv = xp[j];
        tv.x = xv.x + (tv.x - xv.x); tv.y = xv.y + (tv.y - xv.y);
        tv.z = xv.z + (tv.z - xv.z); tv.w = xv.w + (tv.w - xv.w);
      }
      tp[j] = tv;
    }
  }
  sred[tid] = e;
  if (l16 == 0) fidx[row] = (float)id;
  __syncthreads();

  __shared__ float rsum[16];
  if (tid < 16) {
    float s = 0.f;
    #pragma unroll
    for (int k = 0; k < 16; ++k) s += sred[tid * 16 + k];
    rsum[tid] = s;
    if (lvl < 3) rowsq[row0 + tid] = s;
  }
  __syncthreads();
  if (tid == 0) {
    float p = 0.f;
    #pragma unroll
    for (int k = 0; k < 16; ++k) p += rsum[k];
    part[blockIdx.x] = p;
  }

  if (lvl < 3) {
    #pragma unroll
    for (int k = 0; k < 16; ++k) sh[rr][l16 * 16 + k] = nn[k];
    __syncthreads();
    float w[16];
    #pragma unroll
    for (int r = 0; r < 16; ++r) w[r] = sh[r][tid];
    float4* o = reinterpret_cast<float4*>(residT + (size_t)tid * NROWS + row0);
    o[0] = make_float4(w[0], w[1], w[2], w[3]);
    o[1] = make_float4(w[4], w[5], w[6], w[7]);
    o[2] = make_float4(w[8], w[9], w[10], w[11]);
    o[3] = make_float4(w[12], w[13], w[14], w[15]);
  }
}

// ============ loss finalize ============
__global__ __launch_bounds__(256) void k_loss(const float* __restrict__ part,
                                              float* __restrict__ out) {
  __shared__ float s[256];
  const int tid = threadIdx.x;
  float means[4];
  for (int l = 0; l < 4; ++l) {
    float sum = 0.f;
    for (int i = tid; i < 2048; i += 256) sum += part[l * 2048 + i];
    s[tid] = sum;
    __syncthreads();
    for (int st = 128; st > 0; st >>= 1) {
      if (tid < st) s[tid] += s[tid + st];
      __syncthreads();
    }
    means[l] = s[0] * (1.0f / 8388608.0f);  // /(N*D), exact pow2
    __syncthreads();
  }
  if (tid == 0) {
    float t = ((means[0] + means[1]) + means[2]) + means[3];
    float loss = t * 0.25f;
    out[0] = loss;
    out[1] = loss;
  }
}

extern "C" void kernel_launch(void* const* d_in, const int* in_sizes, int n_in,
                              void* d_out, int out_size, void* d_ws, size_t ws_size,
                              hipStream_t stream) {
  const float* x  = (const float*)d_in[0];
  const float* cb = (const float*)d_in[1];
  float* out = (float*)d_out;
  float* ws  = (float*)d_ws;

  // ws layout (float units)
  float* residT = ws;                                   // 8388608
  unsigned long long* best4 = (unsigned long long*)(ws + 8388608);  // 131072 u64
  float* part  = ws + 8388608 + 262144;                 // 4*2048
  float* bv    = ws + 8388608 + 262144 + 8192;          // 4096
  float* rowsq = ws + 8388608 + 262144 + 8192 + 4096;   // 32768
  float* cbT   = ws + 8388608 + 262144 + 8192 + 4096 + 32768;  // 4*262144

  float* tq      = out;                    // total_quant accumulates in d_out
  float* lossout = out + 8388608;
  float* fidx    = out + 8388610;

  hipMemsetAsync(best4, 0xFF, (size_t)NLEV * NROWS * 8, stream);
  k_bnorm<<<16, 256, 0, stream>>>(cb, bv);
  k_tcb<<<256, 256, 0, stream>>>(cb, cbT);
  k_prep<<<2048, 256, 0, stream>>>(x, residT, rowsq);

  for (int l = 0; l < NLEV; ++l) {
    const float* cbl  = cb  + (size_t)l * KCODES * DIM;
    const float* cbTl = cbT + (size_t)l * KCODES * DIM;
    k_argmin<<<2048, 256, 0, stream>>>(residT, cbTl, bv + l * KCODES, rowsq,
                                       best4 + (size_t)l * NROWS);
    k_update<<<2048, 256, 0, stream>>>(residT, cbl, best4 + (size_t)l * NROWS,
                                       tq, fidx + (size_t)l * NROWS,
                                       part + l * 2048, rowsq, x, l);
  }

  k_loss<<<1, 256, 0, stream>>>(part, lossout);
}